// Round 3
// baseline (527.207 us; speedup 1.0000x reference)
//
#include <hip/hip_runtime.h>
#include <hip/hip_bf16.h>

#define SEQ 120
#define CELLS 30          // real cells (ci<5); row ci=5 is pad-only, precomputed
#define RDIM 48
#define BQ 4096
#define MTOT (BQ*CELLS)           // 122880
#define MAIN_BLOCKS (MTOT/64)     // 1920

typedef __bf16 bf16x8 __attribute__((ext_vector_type(8)));
typedef float  f32x4  __attribute__((ext_vector_type(4)));

__device__ __forceinline__ float gelu_f(float x){
  return 0.5f * x * (1.0f + erff(x * 0.7071067811865476f));
}
__device__ __forceinline__ bf16x8 pack8(f32x4 a, f32x4 b){
  bf16x8 r;
  r[0]=(__bf16)a[0]; r[1]=(__bf16)a[1]; r[2]=(__bf16)a[2]; r[3]=(__bf16)a[3];
  r[4]=(__bf16)b[0]; r[5]=(__bf16)b[1]; r[6]=(__bf16)b[2]; r[7]=(__bf16)b[3];
  return r;
}

// ---------------- prep: weight repack (fp32->bf16) + pad-cell readout Gpad ----------------
__global__ void prep_kernel(const float* __restrict__ conv_w, const float* __restrict__ conv_b,
                            const float* __restrict__ P,
                            const float* __restrict__ red_w, const float* __restrict__ red_b,
                            const float* __restrict__ res_w1, const float* __restrict__ res_w2,
                            __bf16* __restrict__ W_bt, __bf16* __restrict__ W_red,
                            __bf16* __restrict__ W1p, __bf16* __restrict__ W2p,
                            float* __restrict__ Gpad)
{
  const int b = blockIdx.x, t = threadIdx.x;
  if (b < 256){
    // W_bt[o][k], k = pos*256 + c  (pos = kh*2+kw)
    #pragma unroll
    for (int u=0;u<4;u++){
      int k = u*256 + t;
      W_bt[b*1024 + k] = (__bf16)conv_w[b*1024 + (k&255)*4 + (k>>8)];
    }
  } else if (b == 256){
    for (int i=t; i<48*256; i+=256) W_red[i] = (__bf16)red_w[i];
  } else if (b < 273){
    int l = b - 257;
    #pragma unroll
    for (int u=0;u<12;u++){
      int idx = u*256 + t;               // j*64 + k
      int j = idx >> 6, k = idx & 63;
      W1p[l*3072 + idx] = (k < 48) ? (__bf16)res_w1[(l*48+j)*48 + k] : (__bf16)0.0f;
    }
  } else if (b < 289){
    int l = b - 273;
    #pragma unroll
    for (int u=0;u<12;u++){
      int idx = u*256 + t;
      int j = idx >> 6, k = idx & 63;
      W2p[l*3072 + idx] = (k < 48) ? (__bf16)res_w2[(l*48+j)*48 + k] : (__bf16)0.0f;
    }
  } else {
    // Gpad: full fp32 readout of the all-pad patch (all 4 positions = P)
    __shared__ float tg[256];
    float z = conv_b[t];
    for (int c=0;c<256;c++){
      const float* w = conv_w + t*1024 + c*4;
      z += (w[0]+w[1]+w[2]+w[3]) * P[c];
    }
    tg[t] = gelu_f(z);
    __syncthreads();
    if (t < 48){
      float g = red_b[t];
      for (int o=0;o<256;o++) g += red_w[t*256+o]*tg[o];
      Gpad[t] = gelu_f(g);
    }
  }
}

// ---------------- main: barrier-free patch-GEMM (M=122880,N=256,K=1024) + gelu
//                  + fused 256->48 GEMM + gelu -> G ----------------
__global__ __launch_bounds__(256, 3) void main_kernel(
    const float* __restrict__ X, const __bf16* __restrict__ W_bt,
    const float* __restrict__ conv_b, const __bf16* __restrict__ W_red,
    const float* __restrict__ red_b, float* __restrict__ G)
{
  __shared__ __align__(16) char sm[32768];   // Y bf16 [64][256], 512B rows, XOR-swizzled
  const int tid  = threadIdx.x;
  const int lane = tid & 63;
  const int wave = tid >> 6;                 // wn 0..3, each wave owns 64 cols
  const int lr = lane & 15, lk = lane >> 4;
  const int m0 = blockIdx.x * 64;

  // per-lane A row base pointers (4 m-fragments); includes lane's k-subslice lk*8
  const float* abase[4];
  #pragma unroll
  for (int mi=0; mi<4; ++mi){
    int m = m0 + mi*16 + lr;
    int bidx = m / 30;
    int cell = m - bidx*30;
    int ci = cell/6, cj = cell - ci*6;       // ci<5 => all 4 tokens < 120
    abase[mi] = X + ((size_t)bidx*SEQ + 24*ci + 2*cj)*256 + lk*8;
  }
  const __bf16* bbase[4];
  #pragma unroll
  for (int ni=0; ni<4; ++ni)
    bbase[ni] = W_bt + (size_t)(wave*64 + ni*16 + lr)*1024 + lk*8;

  f32x4 acc[4][4];
  #pragma unroll
  for (int a=0;a<4;a++)
    #pragma unroll
    for (int b=0;b<4;b++) acc[a][b] = (f32x4){0.f,0.f,0.f,0.f};

  for (int p=0; p<4; ++p){                       // kernel position: token offset {0,1,12,13}
    const int poff = ((p>>1)*12 + (p&1)) * 256;  // 12*kh + kw tokens -> floats
    const float* ap0 = abase[0] + poff;
    const float* ap1 = abase[1] + poff;
    const float* ap2 = abase[2] + poff;
    const float* ap3 = abase[3] + poff;
    #pragma unroll
    for (int ss=0; ss<4; ++ss){                  // s = p*4+ss
      #pragma unroll
      for (int kk=0; kk<2; ++kk){
        const int ko = ss*64 + kk*32;            // element offset within position-slab
        bf16x8 bv[4];
        #pragma unroll
        for (int ni=0; ni<4; ++ni)
          bv[ni] = *(const bf16x8*)(bbase[ni] + p*256 + ko);
        bf16x8 av[4];
        {
          f32x4 u0,u1;
          u0 = *(const f32x4*)(ap0 + ko); u1 = *(const f32x4*)(ap0 + ko + 4); av[0] = pack8(u0,u1);
          u0 = *(const f32x4*)(ap1 + ko); u1 = *(const f32x4*)(ap1 + ko + 4); av[1] = pack8(u0,u1);
          u0 = *(const f32x4*)(ap2 + ko); u1 = *(const f32x4*)(ap2 + ko + 4); av[2] = pack8(u0,u1);
          u0 = *(const f32x4*)(ap3 + ko); u1 = *(const f32x4*)(ap3 + ko + 4); av[3] = pack8(u0,u1);
        }
        #pragma unroll
        for (int mi=0; mi<4; ++mi)
          #pragma unroll
          for (int ni=0; ni<4; ++ni)
            acc[mi][ni] = __builtin_amdgcn_mfma_f32_16x16x32_bf16(av[mi], bv[ni], acc[mi][ni], 0,0,0);
      }
    }
  }

  // epilogue 1: conv bias + gelu -> Y bf16 in LDS (row-swizzled)
  #pragma unroll
  for (int ni=0; ni<4; ++ni){
    const int col = wave*64 + ni*16 + lr;
    const float cb = conv_b[col];
    #pragma unroll
    for (int mi=0; mi<4; ++mi){
      #pragma unroll
      for (int reg=0; reg<4; ++reg){
        int row = mi*16 + lk*4 + reg;
        float y = gelu_f(acc[mi][ni][reg] + cb);
        *(__bf16*)(sm + ((row*512 + col*2) ^ ((row&7)<<4))) = (__bf16)y;
      }
    }
  }
  __syncthreads();

  // GEMM2: G = gelu(Y @ red_w^T + red_b); wave w owns rows [w*16, w*16+16)
  f32x4 acc2[3];
  #pragma unroll
  for (int nf=0;nf<3;nf++) acc2[nf] = (f32x4){0.f,0.f,0.f,0.f};
  const int rowY = wave*16 + lr;
  const int keyY = (rowY&7)<<4;
  #pragma unroll
  for (int kk=0; kk<8; ++kk){
    bf16x8 a2 = *(const bf16x8*)(sm + ((rowY*512 + kk*64 + lk*16) ^ keyY));
    #pragma unroll
    for (int nf=0; nf<3; ++nf){
      bf16x8 b2 = *(const bf16x8*)(W_red + (size_t)(nf*16+lr)*256 + kk*32 + lk*8);
      acc2[nf] = __builtin_amdgcn_mfma_f32_16x16x32_bf16(a2, b2, acc2[nf], 0,0,0);
    }
  }
  #pragma unroll
  for (int nf=0; nf<3; ++nf){
    float rb = red_b[nf*16+lr];
    #pragma unroll
    for (int reg=0; reg<4; ++reg){
      int grow = m0 + wave*16 + lk*4 + reg;
      G[(size_t)grow*RDIM + nf*16 + lr] = gelu_f(acc2[nf][reg] + rb);
    }
  }
}

// ---------------- head: pool + 16 residual blocks (bf16 MFMA, K padded to 64) + linear ----------------
__global__ __launch_bounds__(64) void head_kernel(
    const float* __restrict__ G, const float* __restrict__ Gpad,
    const __bf16* __restrict__ W1p, const __bf16* __restrict__ W2p,
    const float* __restrict__ res_b1, const float* __restrict__ res_b2,
    const float* __restrict__ out_w, const float* __restrict__ out_b,
    float* __restrict__ out)
{
  __shared__ __align__(16) char Hs[16*256];  // [16 rows][64 f32], swizzled, cols 48..63 = 0
  __shared__ __align__(16) char Ys[16*256];
  const int t = threadIdx.x;                 // one wave
  const int lr = t & 15, lk = t >> 4;
  const int b0 = blockIdx.x * 16;

  { // zero pad cols 48..63 (stay zero: layers only write cols<48)
    int row = t >> 2, j4 = 12 + (t & 3);
    int off = (row*256 + j4*16) ^ ((row&7)<<5);
    *(f32x4*)(Hs + off) = (f32x4){0,0,0,0};
    *(f32x4*)(Ys + off) = (f32x4){0,0,0,0};
  }

  // pool: H[b][j] = (sum_{c<30} G[b][c][j] + 6*Gpad[j]) / 36
  #pragma unroll
  for (int pp=0; pp<3; ++pp){
    int idx = pp*64 + t;
    int b = idx / 12, j4 = idx - b*12;
    f32x4 s = ((const f32x4*)Gpad)[j4] * 6.0f;
    const float* g = G + ((size_t)(b0+b)*CELLS)*RDIM + j4*4;
    #pragma unroll
    for (int c=0;c<CELLS;c++) s += *(const f32x4*)(g + c*RDIM);
    s *= (1.0f/36.0f);
    *(f32x4*)(Hs + ((b*256 + j4*16) ^ ((b&7)<<5))) = s;
  }
  __syncthreads();

  const int rowA = lr;
  const int keyA = (rowA&7)<<5;
  for (int l=0; l<16; ++l){
    bf16x8 a[2];
    #pragma unroll
    for (int kk=0;kk<2;kk++){
      f32x4 u0 = *(const f32x4*)(Hs + ((rowA*256 + kk*128 + lk*32) ^ keyA));
      f32x4 u1 = *(const f32x4*)(Hs + ((rowA*256 + kk*128 + lk*32 + 16) ^ keyA));
      a[kk] = pack8(u0,u1);
    }
    #pragma unroll
    for (int nf=0; nf<3; ++nf){
      f32x4 acc = (f32x4){0,0,0,0};
      #pragma unroll
      for (int kk=0;kk<2;kk++){
        bf16x8 bw = *(const bf16x8*)(W1p + ((size_t)l*48 + nf*16 + lr)*64 + kk*32 + lk*8);
        acc = __builtin_amdgcn_mfma_f32_16x16x32_bf16(a[kk], bw, acc, 0,0,0);
      }
      float bj = res_b1[l*48 + nf*16 + lr];
      #pragma unroll
      for (int reg=0; reg<4; ++reg){
        int row = lk*4 + reg;
        *(float*)(Ys + ((row*256 + (nf*16+lr)*4) ^ ((row&7)<<5))) = gelu_f(acc[reg] + bj);
      }
    }
    __syncthreads();
    bf16x8 a2[2];
    #pragma unroll
    for (int kk=0;kk<2;kk++){
      f32x4 u0 = *(const f32x4*)(Ys + ((rowA*256 + kk*128 + lk*32) ^ keyA));
      f32x4 u1 = *(const f32x4*)(Ys + ((rowA*256 + kk*128 + lk*32 + 16) ^ keyA));
      a2[kk] = pack8(u0,u1);
    }
    #pragma unroll
    for (int nf=0; nf<3; ++nf){
      f32x4 acc = (f32x4){0,0,0,0};
      #pragma unroll
      for (int kk=0;kk<2;kk++){
        bf16x8 bw = *(const bf16x8*)(W2p + ((size_t)l*48 + nf*16 + lr)*64 + kk*32 + lk*8);
        acc = __builtin_amdgcn_mfma_f32_16x16x32_bf16(a2[kk], bw, acc, 0,0,0);
      }
      float bj = res_b2[l*48 + nf*16 + lr];
      #pragma unroll
      for (int reg=0; reg<4; ++reg){
        int row = lk*4 + reg;
        float* hp = (float*)(Hs + ((row*256 + (nf*16+lr)*4) ^ ((row&7)<<5)));
        *hp += acc[reg] + bj;
      }
    }
    __syncthreads();
  }

  float s = 0.f;
  #pragma unroll
  for (int i=0;i<12;i++){
    int j = lk*12 + i;
    s += *(const float*)(Hs + ((lr*256 + j*4) ^ ((lr&7)<<5))) * out_w[j];
  }
  s += __shfl_xor(s, 16);
  s += __shfl_xor(s, 32);
  if (lk == 0) out[b0 + lr] = s + out_b[0];
}

extern "C" void kernel_launch(void* const* d_in, const int* in_sizes, int n_in,
                              void* d_out, int out_size, void* d_ws, size_t ws_size,
                              hipStream_t stream) {
  const float* X      = (const float*)d_in[0];
  const float* P      = (const float*)d_in[1];
  const float* conv_w = (const float*)d_in[2];
  const float* conv_b = (const float*)d_in[3];
  const float* red_w  = (const float*)d_in[4];
  const float* red_b  = (const float*)d_in[5];
  const float* res_w1 = (const float*)d_in[6];
  const float* res_b1 = (const float*)d_in[7];
  const float* res_w2 = (const float*)d_in[8];
  const float* res_b2 = (const float*)d_in[9];
  const float* out_w  = (const float*)d_in[10];
  const float* out_b  = (const float*)d_in[11];
  float* out = (float*)d_out;

  char* ws = (char*)d_ws;
  __bf16* W_bt  = (__bf16*)(ws);             // 524288 B
  __bf16* W_red = (__bf16*)(ws + 524288);    // 24576 B
  __bf16* W1p   = (__bf16*)(ws + 548864);    // 98304 B
  __bf16* W2p   = (__bf16*)(ws + 647168);    // 98304 B
  float*  Gpad  = (float*)(ws + 745472);     // 192 B
  float*  G     = (float*)(ws + 1048576);    // 23.6 MB

  prep_kernel<<<290, 256, 0, stream>>>(conv_w, conv_b, P, red_w, red_b, res_w1, res_w2,
                                       W_bt, W_red, W1p, W2p, Gpad);
  main_kernel<<<MAIN_BLOCKS, 256, 0, stream>>>(X, W_bt, conv_b, W_red, red_b, G);
  head_kernel<<<BQ/16, 64, 0, stream>>>(G, Gpad, W1p, W2p, res_b1, res_b2, out_w, out_b, out);
}

// Round 4
// 310.734 us; speedup vs baseline: 1.6967x; 1.6967x over previous
//
#include <hip/hip_runtime.h>
#include <hip/hip_bf16.h>

#define SEQ 120
#define CELLS 30          // real cells (ci<5); row ci=5 is pad-only, precomputed
#define RDIM 48
#define BQ 4096
#define MTOT (BQ*CELLS)           // 122880
#define MAIN_BLOCKS (MTOT/64)     // 1920

typedef __bf16 bf16x8 __attribute__((ext_vector_type(8)));
typedef float  f32x4  __attribute__((ext_vector_type(4)));

__device__ __forceinline__ float gelu_f(float x){
  return 0.5f * x * (1.0f + erff(x * 0.7071067811865476f));
}
__device__ __forceinline__ bf16x8 pack8(f32x4 a, f32x4 b){
  bf16x8 r;
  r[0]=(__bf16)a[0]; r[1]=(__bf16)a[1]; r[2]=(__bf16)a[2]; r[3]=(__bf16)a[3];
  r[4]=(__bf16)b[0]; r[5]=(__bf16)b[1]; r[6]=(__bf16)b[2]; r[7]=(__bf16)b[3];
  return r;
}

// ---------------- prep: weight repack (fp32->bf16) + pad-cell readout Gpad ----------------
__global__ void prep_kernel(const float* __restrict__ conv_w, const float* __restrict__ conv_b,
                            const float* __restrict__ P,
                            const float* __restrict__ red_w, const float* __restrict__ red_b,
                            const float* __restrict__ res_w1, const float* __restrict__ res_w2,
                            __bf16* __restrict__ W_bt, __bf16* __restrict__ W_red,
                            __bf16* __restrict__ W1p, __bf16* __restrict__ W2p,
                            float* __restrict__ Gpad)
{
  const int b = blockIdx.x, t = threadIdx.x;
  if (b < 256){
    // W_bt[o][k], k = pos*256 + c  (pos = kh*2+kw)
    #pragma unroll
    for (int u=0;u<4;u++){
      int k = u*256 + t;
      W_bt[b*1024 + k] = (__bf16)conv_w[b*1024 + (k&255)*4 + (k>>8)];
    }
  } else if (b == 256){
    for (int i=t; i<48*256; i+=256) W_red[i] = (__bf16)red_w[i];
  } else if (b < 273){
    int l = b - 257;
    #pragma unroll
    for (int u=0;u<12;u++){
      int idx = u*256 + t;               // j*64 + k
      int j = idx >> 6, k = idx & 63;
      W1p[l*3072 + idx] = (k < 48) ? (__bf16)res_w1[(l*48+j)*48 + k] : (__bf16)0.0f;
    }
  } else if (b < 289){
    int l = b - 273;
    #pragma unroll
    for (int u=0;u<12;u++){
      int idx = u*256 + t;
      int j = idx >> 6, k = idx & 63;
      W2p[l*3072 + idx] = (k < 48) ? (__bf16)res_w2[(l*48+j)*48 + k] : (__bf16)0.0f;
    }
  } else {
    // Gpad: full fp32 readout of the all-pad patch (all 4 positions = P)
    __shared__ float tg[256];
    float z = conv_b[t];
    for (int c=0;c<256;c++){
      const float* w = conv_w + t*1024 + c*4;
      z += (w[0]+w[1]+w[2]+w[3]) * P[c];
    }
    tg[t] = gelu_f(z);
    __syncthreads();
    if (t < 48){
      float g = red_b[t];
      for (int o=0;o<256;o++) g += red_w[t*256+o]*tg[o];
      Gpad[t] = gelu_f(g);
    }
  }
}

// ---------------- main: reg-staged dbuf patch-GEMM (M=122880,N=256,K=1024) + gelu
//                  + fused 256->48 GEMM + gelu -> G ----------------
__global__ __launch_bounds__(256, 2) void main_kernel(
    const float* __restrict__ X, const __bf16* __restrict__ W_bt,
    const float* __restrict__ conv_b, const __bf16* __restrict__ W_red,
    const float* __restrict__ red_b, float* __restrict__ G)
{
  // LDS: A dbuf bf16 [2][64 rows][128B] = 16KB at [0,16384); Y bf16 [64][512B] = 32KB (reused)
  __shared__ __align__(16) char sm[32768];
  const int tid  = threadIdx.x;
  const int lane = tid & 63;
  const int wave = tid >> 6;                 // each wave owns 64 cols
  const int lr = lane & 15, lk = lane >> 4;
  const int m0 = blockIdx.x * 64;

  // staging role: thread stages row sr, 64B sub-chunk sc, each K-step (BK=64 floats)
  const int sr = tid >> 2, sc = tid & 3;
  {
  }
  const int msr = m0 + sr;
  const int bs = msr / 30;
  const int cs = msr - bs*30;
  const float* srow = X + ((size_t)bs*SEQ + 24*(cs/6) + 2*(cs%6))*256 + sc*16;

  const __bf16* bbase[4];
  #pragma unroll
  for (int ni=0; ni<4; ++ni)
    bbase[ni] = W_bt + (size_t)(wave*64 + ni*16 + lr)*1024 + lk*8;

  // swizzled LDS write offsets (bf16 tile, 16B-granule XOR with row&7)
  const int wr0 = sr*128 + ((sc*32     ) ^ ((sr&7)<<4));
  const int wr1 = sr*128 + ((sc*32 + 16) ^ ((sr&7)<<4));

  f32x4 acc[4][4];
  #pragma unroll
  for (int a=0;a<4;a++)
    #pragma unroll
    for (int b=0;b<4;b++) acc[a][b] = (f32x4){0.f,0.f,0.f,0.f};

  // prologue: stage step 0 into buf0  (step s: p=s>>2 -> token off (p>>1)*12+(p&1); q=s&3)
  {
    f32x4 a0 = *(const f32x4*)(srow + 0);
    f32x4 a1 = *(const f32x4*)(srow + 4);
    f32x4 a2 = *(const f32x4*)(srow + 8);
    f32x4 a3 = *(const f32x4*)(srow + 12);
    *(bf16x8*)(sm + wr0) = pack8(a0,a1);
    *(bf16x8*)(sm + wr1) = pack8(a2,a3);
  }
  __syncthreads();

  for (int s=0; s<16; ++s){
    const int cur = (s&1)*8192;
    const int nxt = 8192 - cur;
    // issue next-step A global loads early (T14: hide HBM latency under compute)
    f32x4 ar0, ar1, ar2, ar3;
    if (s < 15){
      const int s1 = s+1;
      const int off = ((s1>>3)*12 + ((s1>>2)&1))*256 + (s1&3)*64;
      ar0 = *(const f32x4*)(srow + off);
      ar1 = *(const f32x4*)(srow + off + 4);
      ar2 = *(const f32x4*)(srow + off + 8);
      ar3 = *(const f32x4*)(srow + off + 12);
    }
    // B fragments for this step (L2-resident W_bt)
    bf16x8 bv[2][4];
    #pragma unroll
    for (int ks=0; ks<2; ++ks)
      #pragma unroll
      for (int ni=0; ni<4; ++ni)
        bv[ks][ni] = *(const bf16x8*)(bbase[ni] + s*64 + ks*32);
    // A fragments from LDS (conflict-free via granule swizzle)
    bf16x8 av[2][4];
    #pragma unroll
    for (int ks=0; ks<2; ++ks)
      #pragma unroll
      for (int mi=0; mi<4; ++mi){
        const int row = mi*16 + lr;
        av[ks][mi] = *(const bf16x8*)(sm + cur + row*128 + ((ks*64 + lk*16) ^ ((lr&7)<<4)));
      }
    #pragma unroll
    for (int ks=0; ks<2; ++ks)
      #pragma unroll
      for (int mi=0; mi<4; ++mi)
        #pragma unroll
        for (int ni=0; ni<4; ++ni)
          acc[mi][ni] = __builtin_amdgcn_mfma_f32_16x16x32_bf16(av[ks][mi], bv[ks][ni], acc[mi][ni], 0,0,0);
    // write-late: stage next step into the other buffer
    if (s < 15){
      *(bf16x8*)(sm + nxt + wr0) = pack8(ar0, ar1);
      *(bf16x8*)(sm + nxt + wr1) = pack8(ar2, ar3);
    }
    __syncthreads();
  }

  // epilogue 1: conv bias + gelu -> Y bf16 in LDS (row-swizzled), overlapping A buffers
  #pragma unroll
  for (int ni=0; ni<4; ++ni){
    const int col = wave*64 + ni*16 + lr;
    const float cb = conv_b[col];
    #pragma unroll
    for (int mi=0; mi<4; ++mi){
      #pragma unroll
      for (int reg=0; reg<4; ++reg){
        int row = mi*16 + lk*4 + reg;
        float y = gelu_f(acc[mi][ni][reg] + cb);
        *(__bf16*)(sm + ((row*512 + col*2) ^ ((row&7)<<4))) = (__bf16)y;
      }
    }
  }
  __syncthreads();

  // GEMM2: G = gelu(Y @ red_w^T + red_b); wave w owns rows [w*16, w*16+16)
  f32x4 acc2[3];
  #pragma unroll
  for (int nf=0;nf<3;nf++) acc2[nf] = (f32x4){0.f,0.f,0.f,0.f};
  const int rowY = wave*16 + lr;
  const int keyY = (rowY&7)<<4;
  #pragma unroll
  for (int kk=0; kk<8; ++kk){
    bf16x8 a2 = *(const bf16x8*)(sm + ((rowY*512 + kk*64 + lk*16) ^ keyY));
    #pragma unroll
    for (int nf=0; nf<3; ++nf){
      bf16x8 b2 = *(const bf16x8*)(W_red + (size_t)(nf*16+lr)*256 + kk*32 + lk*8);
      acc2[nf] = __builtin_amdgcn_mfma_f32_16x16x32_bf16(a2, b2, acc2[nf], 0,0,0);
    }
  }
  #pragma unroll
  for (int nf=0; nf<3; ++nf){
    float rb = red_b[nf*16+lr];
    #pragma unroll
    for (int reg=0; reg<4; ++reg){
      int grow = m0 + wave*16 + lk*4 + reg;
      G[(size_t)grow*RDIM + nf*16 + lr] = gelu_f(acc2[nf][reg] + rb);
    }
  }
}

// ---------------- head: pool + 16 residual blocks (bf16 MFMA, K padded to 64) + linear ----------------
__global__ __launch_bounds__(64) void head_kernel(
    const float* __restrict__ G, const float* __restrict__ Gpad,
    const __bf16* __restrict__ W1p, const __bf16* __restrict__ W2p,
    const float* __restrict__ res_b1, const float* __restrict__ res_b2,
    const float* __restrict__ out_w, const float* __restrict__ out_b,
    float* __restrict__ out)
{
  __shared__ __align__(16) char Hs[16*256];  // [16 rows][64 f32], swizzled, cols 48..63 = 0
  __shared__ __align__(16) char Ys[16*256];
  const int t = threadIdx.x;                 // one wave
  const int lr = t & 15, lk = t >> 4;
  const int b0 = blockIdx.x * 16;

  { // zero pad cols 48..63 (stay zero: layers only write cols<48)
    int row = t >> 2, j4 = 12 + (t & 3);
    int off = (row*256 + j4*16) ^ ((row&7)<<5);
    *(f32x4*)(Hs + off) = (f32x4){0,0,0,0};
    *(f32x4*)(Ys + off) = (f32x4){0,0,0,0};
  }

  // pool: H[b][j] = (sum_{c<30} G[b][c][j] + 6*Gpad[j]) / 36
  #pragma unroll
  for (int pp=0; pp<3; ++pp){
    int idx = pp*64 + t;
    int b = idx / 12, j4 = idx - b*12;
    f32x4 s = ((const f32x4*)Gpad)[j4] * 6.0f;
    const float* g = G + ((size_t)(b0+b)*CELLS)*RDIM + j4*4;
    #pragma unroll
    for (int c=0;c<CELLS;c++) s += *(const f32x4*)(g + c*RDIM);
    s *= (1.0f/36.0f);
    *(f32x4*)(Hs + ((b*256 + j4*16) ^ ((b&7)<<5))) = s;
  }
  __syncthreads();

  const int rowA = lr;
  const int keyA = (rowA&7)<<5;
  for (int l=0; l<16; ++l){
    bf16x8 a[2];
    #pragma unroll
    for (int kk=0;kk<2;kk++){
      f32x4 u0 = *(const f32x4*)(Hs + ((rowA*256 + kk*128 + lk*32) ^ keyA));
      f32x4 u1 = *(const f32x4*)(Hs + ((rowA*256 + kk*128 + lk*32 + 16) ^ keyA));
      a[kk] = pack8(u0,u1);
    }
    #pragma unroll
    for (int nf=0; nf<3; ++nf){
      f32x4 acc = (f32x4){0,0,0,0};
      #pragma unroll
      for (int kk=0;kk<2;kk++){
        bf16x8 bw = *(const bf16x8*)(W1p + ((size_t)l*48 + nf*16 + lr)*64 + kk*32 + lk*8);
        acc = __builtin_amdgcn_mfma_f32_16x16x32_bf16(a[kk], bw, acc, 0,0,0);
      }
      float bj = res_b1[l*48 + nf*16 + lr];
      #pragma unroll
      for (int reg=0; reg<4; ++reg){
        int row = lk*4 + reg;
        *(float*)(Ys + ((row*256 + (nf*16+lr)*4) ^ ((row&7)<<5))) = gelu_f(acc[reg] + bj);
      }
    }
    __syncthreads();
    bf16x8 a2[2];
    #pragma unroll
    for (int kk=0;kk<2;kk++){
      f32x4 u0 = *(const f32x4*)(Ys + ((rowA*256 + kk*128 + lk*32) ^ keyA));
      f32x4 u1 = *(const f32x4*)(Ys + ((rowA*256 + kk*128 + lk*32 + 16) ^ keyA));
      a2[kk] = pack8(u0,u1);
    }
    #pragma unroll
    for (int nf=0; nf<3; ++nf){
      f32x4 acc = (f32x4){0,0,0,0};
      #pragma unroll
      for (int kk=0;kk<2;kk++){
        bf16x8 bw = *(const bf16x8*)(W2p + ((size_t)l*48 + nf*16 + lr)*64 + kk*32 + lk*8);
        acc = __builtin_amdgcn_mfma_f32_16x16x32_bf16(a2[kk], bw, acc, 0,0,0);
      }
      float bj = res_b2[l*48 + nf*16 + lr];
      #pragma unroll
      for (int reg=0; reg<4; ++reg){
        int row = lk*4 + reg;
        float* hp = (float*)(Hs + ((row*256 + (nf*16+lr)*4) ^ ((row&7)<<5)));
        *hp += acc[reg] + bj;
      }
    }
    __syncthreads();
  }

  float s = 0.f;
  #pragma unroll
  for (int i=0;i<12;i++){
    int j = lk*12 + i;
    s += *(const float*)(Hs + ((lr*256 + j*4) ^ ((lr&7)<<5))) * out_w[j];
  }
  s += __shfl_xor(s, 16);
  s += __shfl_xor(s, 32);
  if (lk == 0) out[b0 + lr] = s + out_b[0];
}

extern "C" void kernel_launch(void* const* d_in, const int* in_sizes, int n_in,
                              void* d_out, int out_size, void* d_ws, size_t ws_size,
                              hipStream_t stream) {
  const float* X      = (const float*)d_in[0];
  const float* P      = (const float*)d_in[1];
  const float* conv_w = (const float*)d_in[2];
  const float* conv_b = (const float*)d_in[3];
  const float* red_w  = (const float*)d_in[4];
  const float* red_b  = (const float*)d_in[5];
  const float* res_w1 = (const float*)d_in[6];
  const float* res_b1 = (const float*)d_in[7];
  const float* res_w2 = (const float*)d_in[8];
  const float* res_b2 = (const float*)d_in[9];
  const float* out_w  = (const float*)d_in[10];
  const float* out_b  = (const float*)d_in[11];
  float* out = (float*)d_out;

  char* ws = (char*)d_ws;
  __bf16* W_bt  = (__bf16*)(ws);             // 524288 B
  __bf16* W_red = (__bf16*)(ws + 524288);    // 24576 B
  __bf16* W1p   = (__bf16*)(ws + 548864);    // 98304 B
  __bf16* W2p   = (__bf16*)(ws + 647168);    // 98304 B
  float*  Gpad  = (float*)(ws + 745472);     // 192 B
  float*  G     = (float*)(ws + 1048576);    // 23.6 MB

  prep_kernel<<<290, 256, 0, stream>>>(conv_w, conv_b, P, red_w, red_b, res_w1, res_w2,
                                       W_bt, W_red, W1p, W2p, Gpad);
  main_kernel<<<MAIN_BLOCKS, 256, 0, stream>>>(X, W_bt, conv_b, W_red, red_b, G);
  head_kernel<<<BQ/16, 64, 0, stream>>>(G, Gpad, W1p, W2p, res_b1, res_b2, out_w, out_b, out);
}

// Round 5
// 289.382 us; speedup vs baseline: 1.8218x; 1.0738x over previous
//
#include <hip/hip_runtime.h>
#include <hip/hip_bf16.h>

#define SEQ 120
#define CELLS 30          // real cells (ci<5); row ci=5 is pad-only, precomputed
#define RDIM 48
#define BQ 4096
#define MTOT (BQ*CELLS)           // 122880
#define MAIN_BLOCKS (MTOT/64)     // 1920

typedef __bf16 bf16x8 __attribute__((ext_vector_type(8)));
typedef float  f32x4  __attribute__((ext_vector_type(4)));

__device__ __forceinline__ float gelu_f(float x){
  return 0.5f * x * (1.0f + erff(x * 0.7071067811865476f));
}
__device__ __forceinline__ bf16x8 pack8(f32x4 a, f32x4 b){
  bf16x8 r;
  r[0]=(__bf16)a[0]; r[1]=(__bf16)a[1]; r[2]=(__bf16)a[2]; r[3]=(__bf16)a[3];
  r[4]=(__bf16)b[0]; r[5]=(__bf16)b[1]; r[6]=(__bf16)b[2]; r[7]=(__bf16)b[3];
  return r;
}

// ---------------- prep: weight repack (fp32->bf16) + pad-cell readout Gpad ----------------
__global__ void prep_kernel(const float* __restrict__ conv_w, const float* __restrict__ conv_b,
                            const float* __restrict__ P,
                            const float* __restrict__ red_w, const float* __restrict__ red_b,
                            const float* __restrict__ res_w1, const float* __restrict__ res_w2,
                            __bf16* __restrict__ W_bt, __bf16* __restrict__ W_red,
                            __bf16* __restrict__ W1p, __bf16* __restrict__ W2p,
                            float* __restrict__ Gpad)
{
  const int b = blockIdx.x, t = threadIdx.x;
  if (b < 256){
    // W_bt[o][k], k = pos*256 + c  (pos = kh*2+kw)
    #pragma unroll
    for (int u=0;u<4;u++){
      int k = u*256 + t;
      W_bt[b*1024 + k] = (__bf16)conv_w[b*1024 + (k&255)*4 + (k>>8)];
    }
  } else if (b == 256){
    for (int i=t; i<48*256; i+=256) W_red[i] = (__bf16)red_w[i];
  } else if (b < 273){
    int l = b - 257;
    #pragma unroll
    for (int u=0;u<12;u++){
      int idx = u*256 + t;               // j*64 + k
      int j = idx >> 6, k = idx & 63;
      W1p[l*3072 + idx] = (k < 48) ? (__bf16)res_w1[(l*48+j)*48 + k] : (__bf16)0.0f;
    }
  } else if (b < 289){
    int l = b - 273;
    #pragma unroll
    for (int u=0;u<12;u++){
      int idx = u*256 + t;
      int j = idx >> 6, k = idx & 63;
      W2p[l*3072 + idx] = (k < 48) ? (__bf16)res_w2[(l*48+j)*48 + k] : (__bf16)0.0f;
    }
  } else {
    // Gpad: full fp32 readout of the all-pad patch (all 4 positions = P)
    __shared__ float tg[256];
    float z = conv_b[t];
    for (int c=0;c<256;c++){
      const float* w = conv_w + t*1024 + c*4;
      z += (w[0]+w[1]+w[2]+w[3]) * P[c];
    }
    tg[t] = gelu_f(z);
    __syncthreads();
    if (t < 48){
      float g = red_b[t];
      for (int o=0;o<256;o++) g += red_w[t*256+o]*tg[o];
      Gpad[t] = gelu_f(g);
    }
  }
}

// ---------------- main: gll-staged dbuf patch-GEMM (M=122880,N=256,K=1024) + gelu
//                  + fused 256->48 GEMM + gelu -> G ----------------
// Pipeline: 2-deep global_load_lds with counted vmcnt across raw barriers (T3/T4-lite).
__global__ __launch_bounds__(256, 3) void main_kernel(
    const float* __restrict__ X, const __bf16* __restrict__ W_bt,
    const float* __restrict__ conv_b, const __bf16* __restrict__ W_red,
    const float* __restrict__ red_b, float* __restrict__ G)
{
  // LDS: A dbuf f32 [2][64 rows][256B] = 32KB; Y bf16 [64][512B] = 32KB reuses same region
  __shared__ __align__(16) char sm[32768];
  const int tid  = threadIdx.x;
  const int lane = tid & 63;
  const int wave = tid >> 6;                 // each wave owns 64 B-cols
  const int lr = lane & 15, lk = lane >> 4;
  const int m0 = blockIdx.x * 64;

  // ---- staging geometry: wave w covers local rows j*16 + w*4 + (lane>>4), 16B chunk (lane&15)
  const int rloc = (wave<<2) + (lane>>4);                       // 0..15
  const int csrc = (lane&15) ^ (((rloc&7)<<1) | ((rloc>>3)&1)); // source-side XOR swizzle
  const char* rp[4];
  #pragma unroll
  for (int j=0;j<4;j++){
    int m = m0 + j*16 + rloc;
    int bs = m / 30;
    int cs = m - bs*30;
    int ci = cs/6, cj = cs - ci*6;           // ci<5 => all 4 tokens < 120
    rp[j] = (const char*)(X + ((size_t)bs*SEQ + 24*ci + 2*cj)*256) + csrc*16;
  }

  const __bf16* bbase[4];
  #pragma unroll
  for (int ni=0; ni<4; ++ni)
    bbase[ni] = W_bt + (size_t)(wave*64 + ni*16 + lr)*1024 + lk*8;

  f32x4 acc[4][4];
  #pragma unroll
  for (int a=0;a<4;a++)
    #pragma unroll
    for (int b=0;b<4;b++) acc[a][b] = (f32x4){0.f,0.f,0.f,0.f};

  // stage step s into buffer d: 4 global_load_lds_dwordx4 per wave (linear dest, swizzled src)
  auto STAGE = [&](int s, int d){
    const int goff = (((s>>3)*12 + ((s>>2)&1)) << 10) + ((s&3) << 8);  // token*1024 + quarter*256
    #pragma unroll
    for (int j=0;j<4;j++){
      __builtin_amdgcn_global_load_lds(
        (const __attribute__((address_space(1))) void*)(rp[j] + goff),
        (__attribute__((address_space(3))) void*)(sm + d*16384 + (j<<12) + (wave<<10)),
        16, 0, 0);
    }
  };

  STAGE(0, 0);
  STAGE(1, 1);

  for (int s=0; s<16; ++s){
    const int cur = (s&1)*16384;
    // buf[s] resident once outstanding <= 4 (stage(s+1)'s loads may remain in flight)
    asm volatile("s_waitcnt vmcnt(4)" ::: "memory");
    __builtin_amdgcn_s_barrier();
    __builtin_amdgcn_sched_barrier(0);
    #pragma unroll
    for (int ks=0; ks<2; ++ks){
      bf16x8 bv[4];
      #pragma unroll
      for (int ni=0; ni<4; ++ni)
        bv[ni] = *(const bf16x8*)(bbase[ni] + s*64 + ks*32);
      bf16x8 av[4];
      #pragma unroll
      for (int mi=0; mi<4; ++mi){
        const int row = mi*16 + lr;
        const int key = ((row&7)<<5) | ((row&8)<<1);
        const char* base = sm + cur + row*256;
        f32x4 u0 = *(const f32x4*)(base + ((ks*128 + lk*32     ) ^ key));
        f32x4 u1 = *(const f32x4*)(base + ((ks*128 + lk*32 + 16) ^ key));
        av[mi] = pack8(u0,u1);
      }
      #pragma unroll
      for (int mi=0; mi<4; ++mi)
        #pragma unroll
        for (int ni=0; ni<4; ++ni)
          acc[mi][ni] = __builtin_amdgcn_mfma_f32_16x16x32_bf16(av[mi], bv[ni], acc[mi][ni], 0,0,0);
    }
    __builtin_amdgcn_s_barrier();            // all waves done reading buf[s&1]
    __builtin_amdgcn_sched_barrier(0);
    if (s < 14) STAGE(s+2, s&1);             // overwrite just-consumed buffer
  }

  // epilogue 1: conv bias + gelu -> Y bf16 in LDS (row-swizzled), reusing the A region
  #pragma unroll
  for (int ni=0; ni<4; ++ni){
    const int col = wave*64 + ni*16 + lr;
    const float cb = conv_b[col];
    #pragma unroll
    for (int mi=0; mi<4; ++mi){
      #pragma unroll
      for (int reg=0; reg<4; ++reg){
        int row = mi*16 + lk*4 + reg;
        float y = gelu_f(acc[mi][ni][reg] + cb);
        *(__bf16*)(sm + ((row*512 + col*2) ^ ((row&7)<<4))) = (__bf16)y;
      }
    }
  }
  __syncthreads();

  // GEMM2: G = gelu(Y @ red_w^T + red_b); wave w owns rows [w*16, w*16+16)
  f32x4 acc2[3];
  #pragma unroll
  for (int nf=0;nf<3;nf++) acc2[nf] = (f32x4){0.f,0.f,0.f,0.f};
  const int rowY = wave*16 + lr;
  const int keyY = (rowY&7)<<4;
  #pragma unroll
  for (int kk=0; kk<8; ++kk){
    bf16x8 a2 = *(const bf16x8*)(sm + ((rowY*512 + kk*64 + lk*16) ^ keyY));
    #pragma unroll
    for (int nf=0; nf<3; ++nf){
      bf16x8 b2 = *(const bf16x8*)(W_red + (size_t)(nf*16+lr)*256 + kk*32 + lk*8);
      acc2[nf] = __builtin_amdgcn_mfma_f32_16x16x32_bf16(a2, b2, acc2[nf], 0,0,0);
    }
  }
  #pragma unroll
  for (int nf=0; nf<3; ++nf){
    float rb = red_b[nf*16+lr];
    #pragma unroll
    for (int reg=0; reg<4; ++reg){
      int grow = m0 + wave*16 + lk*4 + reg;
      G[(size_t)grow*RDIM + nf*16 + lr] = gelu_f(acc2[nf][reg] + rb);
    }
  }
}

// ---------------- head: pool + 16 residual blocks (bf16 MFMA, K padded to 64) + linear ----------------
__global__ __launch_bounds__(64) void head_kernel(
    const float* __restrict__ G, const float* __restrict__ Gpad,
    const __bf16* __restrict__ W1p, const __bf16* __restrict__ W2p,
    const float* __restrict__ res_b1, const float* __restrict__ res_b2,
    const float* __restrict__ out_w, const float* __restrict__ out_b,
    float* __restrict__ out)
{
  __shared__ __align__(16) char Hs[16*256];  // [16 rows][64 f32], swizzled, cols 48..63 = 0
  __shared__ __align__(16) char Ys[16*256];
  const int t = threadIdx.x;                 // one wave
  const int lr = t & 15, lk = t >> 4;
  const int b0 = blockIdx.x * 16;

  { // zero pad cols 48..63 (stay zero: layers only write cols<48)
    int row = t >> 2, j4 = 12 + (t & 3);
    int off = (row*256 + j4*16) ^ ((row&7)<<5);
    *(f32x4*)(Hs + off) = (f32x4){0,0,0,0};
    *(f32x4*)(Ys + off) = (f32x4){0,0,0,0};
  }

  // pool: H[b][j] = (sum_{c<30} G[b][c][j] + 6*Gpad[j]) / 36
  #pragma unroll
  for (int pp=0; pp<3; ++pp){
    int idx = pp*64 + t;
    int b = idx / 12, j4 = idx - b*12;
    f32x4 s = ((const f32x4*)Gpad)[j4] * 6.0f;
    const float* g = G + ((size_t)(b0+b)*CELLS)*RDIM + j4*4;
    #pragma unroll
    for (int c=0;c<CELLS;c++) s += *(const f32x4*)(g + c*RDIM);
    s *= (1.0f/36.0f);
    *(f32x4*)(Hs + ((b*256 + j4*16) ^ ((b&7)<<5))) = s;
  }
  __syncthreads();

  const int rowA = lr;
  const int keyA = (rowA&7)<<5;
  for (int l=0; l<16; ++l){
    bf16x8 a[2];
    #pragma unroll
    for (int kk=0;kk<2;kk++){
      f32x4 u0 = *(const f32x4*)(Hs + ((rowA*256 + kk*128 + lk*32) ^ keyA));
      f32x4 u1 = *(const f32x4*)(Hs + ((rowA*256 + kk*128 + lk*32 + 16) ^ keyA));
      a[kk] = pack8(u0,u1);
    }
    #pragma unroll
    for (int nf=0; nf<3; ++nf){
      f32x4 acc = (f32x4){0,0,0,0};
      #pragma unroll
      for (int kk=0;kk<2;kk++){
        bf16x8 bw = *(const bf16x8*)(W1p + ((size_t)l*48 + nf*16 + lr)*64 + kk*32 + lk*8);
        acc = __builtin_amdgcn_mfma_f32_16x16x32_bf16(a[kk], bw, acc, 0,0,0);
      }
      float bj = res_b1[l*48 + nf*16 + lr];
      #pragma unroll
      for (int reg=0; reg<4; ++reg){
        int row = lk*4 + reg;
        *(float*)(Ys + ((row*256 + (nf*16+lr)*4) ^ ((row&7)<<5))) = gelu_f(acc[reg] + bj);
      }
    }
    __syncthreads();
    bf16x8 a2[2];
    #pragma unroll
    for (int kk=0;kk<2;kk++){
      f32x4 u0 = *(const f32x4*)(Ys + ((rowA*256 + kk*128 + lk*32) ^ keyA));
      f32x4 u1 = *(const f32x4*)(Ys + ((rowA*256 + kk*128 + lk*32 + 16) ^ keyA));
      a2[kk] = pack8(u0,u1);
    }
    #pragma unroll
    for (int nf=0; nf<3; ++nf){
      f32x4 acc = (f32x4){0,0,0,0};
      #pragma unroll
      for (int kk=0;kk<2;kk++){
        bf16x8 bw = *(const bf16x8*)(W2p + ((size_t)l*48 + nf*16 + lr)*64 + kk*32 + lk*8);
        acc = __builtin_amdgcn_mfma_f32_16x16x32_bf16(a2[kk], bw, acc, 0,0,0);
      }
      float bj = res_b2[l*48 + nf*16 + lr];
      #pragma unroll
      for (int reg=0; reg<4; ++reg){
        int row = lk*4 + reg;
        float* hp = (float*)(Hs + ((row*256 + (nf*16+lr)*4) ^ ((row&7)<<5)));
        *hp += acc[reg] + bj;
      }
    }
    __syncthreads();
  }

  float s = 0.f;
  #pragma unroll
  for (int i=0;i<12;i++){
    int j = lk*12 + i;
    s += *(const float*)(Hs + ((lr*256 + j*4) ^ ((lr&7)<<5))) * out_w[j];
  }
  s += __shfl_xor(s, 16);
  s += __shfl_xor(s, 32);
  if (lk == 0) out[b0 + lr] = s + out_b[0];
}

extern "C" void kernel_launch(void* const* d_in, const int* in_sizes, int n_in,
                              void* d_out, int out_size, void* d_ws, size_t ws_size,
                              hipStream_t stream) {
  const float* X      = (const float*)d_in[0];
  const float* P      = (const float*)d_in[1];
  const float* conv_w = (const float*)d_in[2];
  const float* conv_b = (const float*)d_in[3];
  const float* red_w  = (const float*)d_in[4];
  const float* red_b  = (const float*)d_in[5];
  const float* res_w1 = (const float*)d_in[6];
  const float* res_b1 = (const float*)d_in[7];
  const float* res_w2 = (const float*)d_in[8];
  const float* res_b2 = (const float*)d_in[9];
  const float* out_w  = (const float*)d_in[10];
  const float* out_b  = (const float*)d_in[11];
  float* out = (float*)d_out;

  char* ws = (char*)d_ws;
  __bf16* W_bt  = (__bf16*)(ws);             // 524288 B
  __bf16* W_red = (__bf16*)(ws + 524288);    // 24576 B
  __bf16* W1p   = (__bf16*)(ws + 548864);    // 98304 B
  __bf16* W2p   = (__bf16*)(ws + 647168);    // 98304 B
  float*  Gpad  = (float*)(ws + 745472);     // 192 B
  float*  G     = (float*)(ws + 1048576);    // 23.6 MB

  prep_kernel<<<290, 256, 0, stream>>>(conv_w, conv_b, P, red_w, red_b, res_w1, res_w2,
                                       W_bt, W_red, W1p, W2p, Gpad);
  main_kernel<<<MAIN_BLOCKS, 256, 0, stream>>>(X, W_bt, conv_b, W_red, red_b, G);
  head_kernel<<<BQ/16, 64, 0, stream>>>(G, Gpad, W1p, W2p, res_b1, res_b2, out_w, out_b, out);
}

// Round 6
// 262.215 us; speedup vs baseline: 2.0106x; 1.1036x over previous
//
#include <hip/hip_runtime.h>
#include <hip/hip_bf16.h>

#define SEQ 120
#define CELLS 30          // real cells (ci<5); row ci=5 is pad-only, precomputed
#define RDIM 48
#define BQ 4096
#define MTOT (BQ*CELLS)           // 122880
#define MAIN_BLOCKS (MTOT/128)    // 960

typedef __bf16 bf16x8 __attribute__((ext_vector_type(8)));
typedef float  f32x4  __attribute__((ext_vector_type(4)));

__device__ __forceinline__ float gelu_f(float x){
  return 0.5f * x * (1.0f + erff(x * 0.7071067811865476f));
}
__device__ __forceinline__ bf16x8 pack8(f32x4 a, f32x4 b){
  bf16x8 r;
  r[0]=(__bf16)a[0]; r[1]=(__bf16)a[1]; r[2]=(__bf16)a[2]; r[3]=(__bf16)a[3];
  r[4]=(__bf16)b[0]; r[5]=(__bf16)b[1]; r[6]=(__bf16)b[2]; r[7]=(__bf16)b[3];
  return r;
}

// ---------------- prep: weight repack (fp32->bf16) + pad-cell readout Gpad ----------------
__global__ void prep_kernel(const float* __restrict__ conv_w, const float* __restrict__ conv_b,
                            const float* __restrict__ P,
                            const float* __restrict__ red_w, const float* __restrict__ red_b,
                            const float* __restrict__ res_w1, const float* __restrict__ res_w2,
                            __bf16* __restrict__ W_bt, __bf16* __restrict__ W_red,
                            __bf16* __restrict__ W1p, __bf16* __restrict__ W2p,
                            float* __restrict__ Gpad)
{
  const int b = blockIdx.x, t = threadIdx.x;
  if (b < 256){
    // W_bt[o][k], k = pos*256 + c  (pos = kh*2+kw)
    #pragma unroll
    for (int u=0;u<4;u++){
      int k = u*256 + t;
      W_bt[b*1024 + k] = (__bf16)conv_w[b*1024 + (k&255)*4 + (k>>8)];
    }
  } else if (b == 256){
    for (int i=t; i<48*256; i+=256) W_red[i] = (__bf16)red_w[i];
  } else if (b < 273){
    int l = b - 257;
    #pragma unroll
    for (int u=0;u<12;u++){
      int idx = u*256 + t;               // j*64 + k
      int j = idx >> 6, k = idx & 63;
      W1p[l*3072 + idx] = (k < 48) ? (__bf16)res_w1[(l*48+j)*48 + k] : (__bf16)0.0f;
    }
  } else if (b < 289){
    int l = b - 273;
    #pragma unroll
    for (int u=0;u<12;u++){
      int idx = u*256 + t;
      int j = idx >> 6, k = idx & 63;
      W2p[l*3072 + idx] = (k < 48) ? (__bf16)res_w2[(l*48+j)*48 + k] : (__bf16)0.0f;
    }
  } else {
    // Gpad: full fp32 readout of the all-pad patch (all 4 positions = P)
    __shared__ float tg[256];
    float z = conv_b[t];
    for (int c=0;c<256;c++){
      const float* w = conv_w + t*1024 + c*4;
      z += (w[0]+w[1]+w[2]+w[3]) * P[c];
    }
    tg[t] = gelu_f(z);
    __syncthreads();
    if (t < 48){
      float g = red_b[t];
      for (int o=0;o<256;o++) g += red_w[t*256+o]*tg[o];
      Gpad[t] = gelu_f(g);
    }
  }
}

// ---------------- main: dual-LDS-staged dbuf patch-GEMM (M=122880,N=256,K=1024) + gelu
//                  + fused 256->48 GEMM + gelu -> G ----------------
// B now staged in LDS once per block-step (shared by 8 waves) — kills the per-wave L2 B-refetch
// that bounded R4/R5 (96 KB/CU-step from L2 vs 56 B/cy budget).
__global__ __launch_bounds__(512, 2) void main_kernel(
    const float* __restrict__ X, const __bf16* __restrict__ W_bt,
    const float* __restrict__ conv_b, const __bf16* __restrict__ W_red,
    const float* __restrict__ red_b, float* __restrict__ G)
{
  // LDS: A f32 dbuf [2][128 rows][256B] = 64KB at [0,64K); B bf16 dbuf [2][256 cols][128B] = 64KB at [64K,128K)
  // Y bf16 [128][512B] = 64KB reuses [0,64K) after the K-loop.
  __shared__ __align__(16) char sm[131072];
  const int tid  = threadIdx.x;
  const int lane = tid & 63;
  const int wave = tid >> 6;                 // 0..7; wave grid 2(M) x 4(N)
  const int wm = wave >> 2, wn = wave & 3;
  const int lr = lane & 15, lk = lane >> 4;
  const int m0 = blockIdx.x * 128;

  // ---- A staging: instr j of wave w covers rows (j*8+w)*4 .. +4 (1KB linear dest);
  //      source chunk pre-swizzled so the LDS read side can XOR-deswizzle (m173 pattern).
  const char* rpA[4];
  #pragma unroll
  for (int j=0;j<4;j++){
    int row = (j*8 + wave)*4 + (lane>>4);
    int m = m0 + row;
    int bs = m / 30;
    int cs = m - bs*30;
    int ci = cs/6, cj = cs - ci*6;           // ci<5 => all 4 tokens < 120
    int key = ((row&7)<<1) | ((row&8)>>3);   // 4-bit chunk key, bijective over lr
    int chunk = (lane&15) ^ key;
    rpA[j] = (const char*)(X + ((size_t)bs*SEQ + 24*ci + 2*cj)*256) + chunk*16;
  }
  // ---- B staging: instr j of wave w covers cols j*64 + w*8 .. +8 (1KB linear dest)
  const char* rpB[4];
  #pragma unroll
  for (int j=0;j<4;j++){
    int col = j*64 + wave*8 + (lane>>3);
    int chunk = (lane&7) ^ (lane>>3);        // ^(col&7), col&7 == lane>>3
    rpB[j] = (const char*)W_bt + (size_t)col*2048 + chunk*16;
  }

  f32x4 acc[4][4];
  #pragma unroll
  for (int a=0;a<4;a++)
    #pragma unroll
    for (int b=0;b<4;b++) acc[a][b] = (f32x4){0.f,0.f,0.f,0.f};

  // stage step s into buffer d: 8 global_load_lds_dwordx4 per wave (4 A + 4 B)
  auto STAGE = [&](int s, int d){
    const int goff = (((s>>3)*12 + ((s>>2)&1)) << 10) + ((s&3) << 8);  // bytes into patch row
    #pragma unroll
    for (int j=0;j<4;j++){
      __builtin_amdgcn_global_load_lds(
        (const __attribute__((address_space(1))) void*)(rpA[j] + goff),
        (__attribute__((address_space(3))) void*)(sm + d*32768 + (j*8 + wave)*1024),
        16, 0, 0);
    }
    #pragma unroll
    for (int j=0;j<4;j++){
      __builtin_amdgcn_global_load_lds(
        (const __attribute__((address_space(1))) void*)(rpB[j] + s*128),
        (__attribute__((address_space(3))) void*)(sm + 65536 + d*32768 + (j*64 + wave*8)*128),
        16, 0, 0);
    }
  };

  STAGE(0, 0);
  STAGE(1, 1);

  for (int s=0; s<16; ++s){
    const int abuf = (s&1)*32768;
    const int bbuf = 65536 + (s&1)*32768;
    // steady state: leave STAGE(s+1)'s 8 loads in flight; s=15 has nothing behind it -> drain
    if (s < 15) asm volatile("s_waitcnt vmcnt(8)" ::: "memory");
    else        asm volatile("s_waitcnt vmcnt(0)" ::: "memory");
    __builtin_amdgcn_s_barrier();
    __builtin_amdgcn_sched_barrier(0);
    #pragma unroll
    for (int ks=0; ks<2; ++ks){
      bf16x8 bv[4];
      #pragma unroll
      for (int ni=0; ni<4; ++ni){
        const int col = wn*64 + ni*16 + lr;
        bv[ni] = *(const bf16x8*)(sm + bbuf + col*128 + ((ks*64 + lk*16) ^ ((col&7)<<4)));
      }
      bf16x8 av[4];
      #pragma unroll
      for (int mi=0; mi<4; ++mi){
        const int row = wm*64 + mi*16 + lr;
        const int key = ((row&7)<<5) | ((row&8)<<1);
        const char* base = sm + abuf + row*256;
        f32x4 u0 = *(const f32x4*)(base + ((ks*128 + lk*32     ) ^ key));
        f32x4 u1 = *(const f32x4*)(base + ((ks*128 + lk*32 + 16) ^ key));
        av[mi] = pack8(u0,u1);
      }
      #pragma unroll
      for (int mi=0; mi<4; ++mi)
        #pragma unroll
        for (int ni=0; ni<4; ++ni)
          acc[mi][ni] = __builtin_amdgcn_mfma_f32_16x16x32_bf16(av[mi], bv[ni], acc[mi][ni], 0,0,0);
    }
    __builtin_amdgcn_s_barrier();            // all waves done reading buf[s&1]
    __builtin_amdgcn_sched_barrier(0);
    if (s < 14) STAGE(s+2, s&1);             // overwrite just-consumed buffer
  }

  // epilogue 1: conv bias + gelu -> Y bf16 [128][256] in LDS (row-swizzled), reusing A region
  #pragma unroll
  for (int ni=0; ni<4; ++ni){
    const int col = wn*64 + ni*16 + lr;
    const float cb = conv_b[col];
    #pragma unroll
    for (int mi=0; mi<4; ++mi){
      #pragma unroll
      for (int reg=0; reg<4; ++reg){
        int row = wm*64 + mi*16 + lk*4 + reg;
        float y = gelu_f(acc[mi][ni][reg] + cb);
        *(__bf16*)(sm + ((row*512 + col*2) ^ ((row&7)<<4))) = (__bf16)y;
      }
    }
  }
  __syncthreads();

  // GEMM2: G = gelu(Y @ red_w^T + red_b); wave w owns rows [w*16, w*16+16)
  f32x4 acc2[3];
  #pragma unroll
  for (int nf=0;nf<3;nf++) acc2[nf] = (f32x4){0.f,0.f,0.f,0.f};
  const int rowY = wave*16 + lr;
  const int keyY = (rowY&7)<<4;
  #pragma unroll
  for (int kk=0; kk<8; ++kk){
    bf16x8 a2 = *(const bf16x8*)(sm + ((rowY*512 + kk*64 + lk*16) ^ keyY));
    #pragma unroll
    for (int nf=0; nf<3; ++nf){
      bf16x8 b2 = *(const bf16x8*)(W_red + (size_t)(nf*16+lr)*256 + kk*32 + lk*8);
      acc2[nf] = __builtin_amdgcn_mfma_f32_16x16x32_bf16(a2, b2, acc2[nf], 0,0,0);
    }
  }
  #pragma unroll
  for (int nf=0; nf<3; ++nf){
    float rb = red_b[nf*16+lr];
    #pragma unroll
    for (int reg=0; reg<4; ++reg){
      int grow = m0 + wave*16 + lk*4 + reg;
      G[(size_t)grow*RDIM + nf*16 + lr] = gelu_f(acc2[nf][reg] + rb);
    }
  }
}

// ---------------- head: pool + 16 residual blocks (bf16 MFMA, K padded to 64) + linear ----------------
__global__ __launch_bounds__(64) void head_kernel(
    const float* __restrict__ G, const float* __restrict__ Gpad,
    const __bf16* __restrict__ W1p, const __bf16* __restrict__ W2p,
    const float* __restrict__ res_b1, const float* __restrict__ res_b2,
    const float* __restrict__ out_w, const float* __restrict__ out_b,
    float* __restrict__ out)
{
  __shared__ __align__(16) char Hs[16*256];  // [16 rows][64 f32], swizzled, cols 48..63 = 0
  __shared__ __align__(16) char Ys[16*256];
  const int t = threadIdx.x;                 // one wave
  const int lr = t & 15, lk = t >> 4;
  const int b0 = blockIdx.x * 16;

  { // zero pad cols 48..63 (stay zero: layers only write cols<48)
    int row = t >> 2, j4 = 12 + (t & 3);
    int off = (row*256 + j4*16) ^ ((row&7)<<5);
    *(f32x4*)(Hs + off) = (f32x4){0,0,0,0};
    *(f32x4*)(Ys + off) = (f32x4){0,0,0,0};
  }

  // pool: H[b][j] = (sum_{c<30} G[b][c][j] + 6*Gpad[j]) / 36
  #pragma unroll
  for (int pp=0; pp<3; ++pp){
    int idx = pp*64 + t;
    int b = idx / 12, j4 = idx - b*12;
    f32x4 s = ((const f32x4*)Gpad)[j4] * 6.0f;
    const float* g = G + ((size_t)(b0+b)*CELLS)*RDIM + j4*4;
    #pragma unroll
    for (int c=0;c<CELLS;c++) s += *(const f32x4*)(g + c*RDIM);
    s *= (1.0f/36.0f);
    *(f32x4*)(Hs + ((b*256 + j4*16) ^ ((b&7)<<5))) = s;
  }
  __syncthreads();

  const int rowA = lr;
  const int keyA = (rowA&7)<<5;
  for (int l=0; l<16; ++l){
    bf16x8 a[2];
    #pragma unroll
    for (int kk=0;kk<2;kk++){
      f32x4 u0 = *(const f32x4*)(Hs + ((rowA*256 + kk*128 + lk*32) ^ keyA));
      f32x4 u1 = *(const f32x4*)(Hs + ((rowA*256 + kk*128 + lk*32 + 16) ^ keyA));
      a[kk] = pack8(u0,u1);
    }
    #pragma unroll
    for (int nf=0; nf<3; ++nf){
      f32x4 acc = (f32x4){0,0,0,0};
      #pragma unroll
      for (int kk=0;kk<2;kk++){
        bf16x8 bw = *(const bf16x8*)(W1p + ((size_t)l*48 + nf*16 + lr)*64 + kk*32 + lk*8);
        acc = __builtin_amdgcn_mfma_f32_16x16x32_bf16(a[kk], bw, acc, 0,0,0);
      }
      float bj = res_b1[l*48 + nf*16 + lr];
      #pragma unroll
      for (int reg=0; reg<4; ++reg){
        int row = lk*4 + reg;
        *(float*)(Ys + ((row*256 + (nf*16+lr)*4) ^ ((row&7)<<5))) = gelu_f(acc[reg] + bj);
      }
    }
    __syncthreads();
    bf16x8 a2[2];
    #pragma unroll
    for (int kk=0;kk<2;kk++){
      f32x4 u0 = *(const f32x4*)(Ys + ((rowA*256 + kk*128 + lk*32) ^ keyA));
      f32x4 u1 = *(const f32x4*)(Ys + ((rowA*256 + kk*128 + lk*32 + 16) ^ keyA));
      a2[kk] = pack8(u0,u1);
    }
    #pragma unroll
    for (int nf=0; nf<3; ++nf){
      f32x4 acc = (f32x4){0,0,0,0};
      #pragma unroll
      for (int kk=0;kk<2;kk++){
        bf16x8 bw = *(const bf16x8*)(W2p + ((size_t)l*48 + nf*16 + lr)*64 + kk*32 + lk*8);
        acc = __builtin_amdgcn_mfma_f32_16x16x32_bf16(a2[kk], bw, acc, 0,0,0);
      }
      float bj = res_b2[l*48 + nf*16 + lr];
      #pragma unroll
      for (int reg=0; reg<4; ++reg){
        int row = lk*4 + reg;
        float* hp = (float*)(Hs + ((row*256 + (nf*16+lr)*4) ^ ((row&7)<<5)));
        *hp += acc[reg] + bj;
      }
    }
    __syncthreads();
  }

  float s = 0.f;
  #pragma unroll
  for (int i=0;i<12;i++){
    int j = lk*12 + i;
    s += *(const float*)(Hs + ((lr*256 + j*4) ^ ((lr&7)<<5))) * out_w[j];
  }
  s += __shfl_xor(s, 16);
  s += __shfl_xor(s, 32);
  if (lk == 0) out[b0 + lr] = s + out_b[0];
}

extern "C" void kernel_launch(void* const* d_in, const int* in_sizes, int n_in,
                              void* d_out, int out_size, void* d_ws, size_t ws_size,
                              hipStream_t stream) {
  const float* X      = (const float*)d_in[0];
  const float* P      = (const float*)d_in[1];
  const float* conv_w = (const float*)d_in[2];
  const float* conv_b = (const float*)d_in[3];
  const float* red_w  = (const float*)d_in[4];
  const float* red_b  = (const float*)d_in[5];
  const float* res_w1 = (const float*)d_in[6];
  const float* res_b1 = (const float*)d_in[7];
  const float* res_w2 = (const float*)d_in[8];
  const float* res_b2 = (const float*)d_in[9];
  const float* out_w  = (const float*)d_in[10];
  const float* out_b  = (const float*)d_in[11];
  float* out = (float*)d_out;

  char* ws = (char*)d_ws;
  __bf16* W_bt  = (__bf16*)(ws);             // 524288 B
  __bf16* W_red = (__bf16*)(ws + 524288);    // 24576 B
  __bf16* W1p   = (__bf16*)(ws + 548864);    // 98304 B
  __bf16* W2p   = (__bf16*)(ws + 647168);    // 98304 B
  float*  Gpad  = (float*)(ws + 745472);     // 192 B
  float*  G     = (float*)(ws + 1048576);    // 23.6 MB

  prep_kernel<<<290, 256, 0, stream>>>(conv_w, conv_b, P, red_w, red_b, res_w1, res_w2,
                                       W_bt, W_red, W1p, W2p, Gpad);
  main_kernel<<<MAIN_BLOCKS, 512, 0, stream>>>(X, W_bt, conv_b, W_red, red_b, G);
  head_kernel<<<BQ/16, 64, 0, stream>>>(G, Gpad, W1p, W2p, res_b1, res_b2, out_w, out_b, out);
}